// Round 1
// baseline (2367.530 us; speedup 1.0000x reference)
//
#include <hip/hip_runtime.h>

// Problem constants (from reference):
//   x: [16, 256, 4096] f32, w: [256, 256, 3] f32, bias: [256] f32
//   out: [16, 256, 8192] f32
// Math (derived from dilated conv + FIR [0.25,0.75,0.75,0.25]):
//   y[2s]   = sum_ci w0*x[s-1] + w2*x[s]
//   y[2s+1] = sum_ci w1*x[s]
//   out[2t]   = 0.25*y[2t-1] + 0.75*y[2t] + 0.75*y[2t+1] + 0.25*y[2t+2]
//   out[2t+1] = 0.25*y[2t]   + 0.75*y[2t+1] + 0.75*y[2t+2] + 0.25*y[2t+3]
// Per-thread: 8 consecutive t; partial sums s[k]=Σ w1*xa[k] (k=0..9),
//             g[k]=Σ w0*xa[k]+w2*xa[k+1] (k=0..8) over xa = x[t0-1 .. t0+8].

#define N_   16
#define CI_  256
#define CO_  256
#define D_   4096
#define DO_  8192

__global__ __launch_bounds__(256) void upconv_fir_f32(
    const float* __restrict__ x, const float* __restrict__ w,
    const float* __restrict__ bias, float* __restrict__ out)
{
    __shared__ float ws[CI_][4];   // weights for this block's co, padded to 4

    const int tid = threadIdx.x;
    const int co  = blockIdx.y;
    const int n   = blockIdx.z;

    // Stage this co's 256x3 weights into LDS (one ci per thread).
    {
        const float* wc = w + (size_t)co * CI_ * 3;
        ws[tid][0] = wc[tid * 3 + 0];
        ws[tid][1] = wc[tid * 3 + 1];
        ws[tid][2] = wc[tid * 3 + 2];
        ws[tid][3] = 0.f;
    }
    __syncthreads();

    const int t0 = (blockIdx.x * 256 + tid) * 8;   // 8 t-values per thread
    const float* xn = x + (size_t)n * CI_ * D_;

    float s[10], g[9];
    #pragma unroll
    for (int k = 0; k < 10; ++k) s[k] = 0.f;
    #pragma unroll
    for (int k = 0; k < 9; ++k) g[k] = 0.f;

    #pragma unroll 2
    for (int ci = 0; ci < CI_; ++ci) {
        const float* xr = xn + ci * D_;
        float4 va = *(const float4*)(xr + t0);
        float4 vb = *(const float4*)(xr + t0 + 4);
        float  xm = (t0 > 0)       ? xr[t0 - 1] : 0.f;
        float  xp = (t0 + 8 < D_)  ? xr[t0 + 8] : 0.f;

        float4 wv = *(const float4*)(&ws[ci][0]);  // broadcast ds_read_b128
        const float w0 = wv.x, w1 = wv.y, w2 = wv.z;

        float xa[10];
        xa[0] = xm;
        xa[1] = va.x; xa[2] = va.y; xa[3] = va.z; xa[4] = va.w;
        xa[5] = vb.x; xa[6] = vb.y; xa[7] = vb.z; xa[8] = vb.w;
        xa[9] = xp;

        #pragma unroll
        for (int k = 0; k < 10; ++k) s[k] += w1 * xa[k];
        #pragma unroll
        for (int k = 0; k < 9; ++k)  g[k] += w0 * xa[k] + w2 * xa[k + 1];
    }

    const float b = bias[co];
    float o16[16];
    #pragma unroll
    for (int tt = 0; tt < 8; ++tt) {
        // out_even(t) = 0.25*s[tt] + 0.75*g[tt] + 0.75*s[tt+1] + 0.25*g[tt+1]
        // out_odd(t)  = 0.25*g[tt] + 0.75*s[tt+1] + 0.75*g[tt+1] + 0.25*s[tt+2]
        o16[2 * tt]     = 0.25f * (s[tt] + g[tt + 1]) + 0.75f * (g[tt] + s[tt + 1]) + b;
        o16[2 * tt + 1] = 0.25f * (g[tt] + s[tt + 2]) + 0.75f * (s[tt + 1] + g[tt + 1]) + b;
    }

    float* ob = out + ((size_t)n * CO_ + co) * DO_ + 2 * t0;
    *(float4*)(ob + 0)  = make_float4(o16[0],  o16[1],  o16[2],  o16[3]);
    *(float4*)(ob + 4)  = make_float4(o16[4],  o16[5],  o16[6],  o16[7]);
    *(float4*)(ob + 8)  = make_float4(o16[8],  o16[9],  o16[10], o16[11]);
    *(float4*)(ob + 12) = make_float4(o16[12], o16[13], o16[14], o16[15]);
}

extern "C" void kernel_launch(void* const* d_in, const int* in_sizes, int n_in,
                              void* d_out, int out_size, void* d_ws, size_t ws_size,
                              hipStream_t stream) {
    const float* x  = (const float*)d_in[0];
    const float* w  = (const float*)d_in[1];
    const float* b  = (const float*)d_in[2];
    float* out      = (float*)d_out;

    // grid: (t-chunks of 2048, co, n) ; 8 t per thread * 256 threads = 2048 t
    dim3 grid(D_ / 2048, CO_, N_);
    upconv_fir_f32<<<grid, 256, 0, stream>>>(x, w, b, out);
}

// Round 2
// 244.756 us; speedup vs baseline: 9.6730x; 9.6730x over previous
//
#include <hip/hip_runtime.h>
#include <hip/hip_bf16.h>

#define N_   16
#define CI_  256
#define CO_  256
#define D_   4096
#define DO_  8192
#define KTOT 768            // 3 taps (j outer) x 256 ci
#define XTROWS 4098         // 4096 t + 1 zero pad row each side
#define WT_ELEMS (512 * KTOT)
#define XT_ELEMS ((size_t)N_ * XTROWS * 256)

typedef short frag8 __attribute__((ext_vector_type(8)));   // 8 bf16 (4 VGPR)
typedef float facc4 __attribute__((ext_vector_type(4)));   // 4 f32 acc

static __device__ __forceinline__ unsigned short f2bf(float f) {
    union { __hip_bfloat16 h; unsigned short u; } cv;
    cv.h = __float2bfloat16(f);
    return cv.u;
}

static __device__ __forceinline__ void async16(unsigned short* lds, const unsigned short* g) {
    __builtin_amdgcn_global_load_lds(
        (const __attribute__((address_space(1))) unsigned int*)g,
        (__attribute__((address_space(3))) unsigned int*)lds, 16, 0, 0);
}

// ---------------- prep 1: effective bf16 weights -------------------------
// Wt[m = co*2+phase][k = j*256 + ci]; j=0 -> x[t-1], j=1 -> x[t], j=2 -> x[t+1]
__global__ __launch_bounds__(256) void prep_wt(const float* __restrict__ w,
                                               unsigned short* __restrict__ Wt) {
    const int ci = threadIdx.x;
    const int co = blockIdx.x;
    const float* wp = w + ((size_t)co * CI_ + ci) * 3;
    const float w0 = wp[0], w1 = wp[1], w2 = wp[2];
    const float e0 = 0.25f * w1 + 0.75f * w0;
    const float e1 = 0.75f * w2 + 0.75f * w1 + 0.25f * w0;
    const float e2 = 0.25f * w2;
    const float o0 = 0.25f * w0;
    const float o1 = 0.25f * w2 + 0.75f * w1 + 0.75f * w0;
    const float o2 = 0.75f * w2 + 0.25f * w1;
    unsigned short* pe = Wt + (size_t)(co * 2 + 0) * KTOT;
    unsigned short* po = Wt + (size_t)(co * 2 + 1) * KTOT;
    pe[0 * 256 + ci] = f2bf(e0); pe[1 * 256 + ci] = f2bf(e1); pe[2 * 256 + ci] = f2bf(e2);
    po[0 * 256 + ci] = f2bf(o0); po[1 * 256 + ci] = f2bf(o1); po[2 * 256 + ci] = f2bf(o2);
}

// ---------------- prep 2: x [n][ci][t] f32 -> x_t [n][t+1][ci] bf16 ------
__global__ __launch_bounds__(256) void prep_xt(const float* __restrict__ x,
                                               unsigned short* __restrict__ xt) {
    __shared__ unsigned short Ls[64][258];   // pitch 258: bank = t%32, 2-way (free)
    const int tid  = threadIdx.x;
    const int lane = tid & 63;
    const int qw   = tid >> 6;               // 0..3
    const int t0 = blockIdx.x * 64;
    const int n  = blockIdx.y;
    const float* xn = x + (size_t)n * CI_ * D_;
    unsigned short* slab = xt + (size_t)n * XTROWS * 256;

    // zero pad rows (t = -1 and t = 4096)
    if (t0 == 0 && tid < 128)        ((unsigned int*)slab)[tid] = 0u;
    if (t0 == D_ - 64 && tid < 128)  ((unsigned int*)(slab + (size_t)(XTROWS - 1) * 256))[tid] = 0u;

    #pragma unroll 4
    for (int r = 0; r < 64; ++r) {
        int ci = r * 4 + qw;
        Ls[lane][ci] = f2bf(xn[(size_t)ci * D_ + t0 + lane]);  // coalesced 256B/qwave
    }
    __syncthreads();
    #pragma unroll 4
    for (int r = 0; r < 16; ++r) {
        int tl  = r * 4 + qw;
        int ci0 = lane * 4;
        unsigned int lo = *(const unsigned int*)(&Ls[tl][ci0]);
        unsigned int hi = *(const unsigned int*)(&Ls[tl][ci0 + 2]);
        unsigned int* op = (unsigned int*)(slab + (size_t)(1 + t0 + tl) * 256 + ci0);
        op[0] = lo; op[1] = hi;                               // 512B/qwave coalesced
    }
}

// ---------------- main: 128x128-tile bf16 MFMA GEMM + fused epilogue -----
// C[m][t] = sum_k Wt[m][k] * B[k][t],  B[k][t] = xt_flat[t*256 + k] (overlap trick)
__global__ __launch_bounds__(256) void gemm_upfir(
    const unsigned short* __restrict__ Wt, const unsigned short* __restrict__ xt,
    const float* __restrict__ bias, float* __restrict__ out)
{
    __shared__ __align__(16) unsigned short As[128 * 32];
    __shared__ __align__(16) unsigned short Bs[128 * 32];

    const int tid  = threadIdx.x;
    const int lane = tid & 63;
    const int wid  = tid >> 6;
    const int quad = lane >> 4;
    const int l16  = lane & 15;

    const int bt0 = blockIdx.x * 128;   // t tile
    const int bm0 = blockIdx.y * 128;   // m tile (m = co*2+phase)
    const int n   = blockIdx.z;

    // staging: 16 x 1KB global_load_lds per K-step; waves 0,1 -> As, 2,3 -> Bs
    // LDS chunk c_slot holds global chunk c_slot ^ ((row>>1)&3)  (bank swizzle)
    const int srow = lane >> 2;          // row within a 16-row instr
    const int slot = lane & 3;
    const unsigned short* gsrc;
    unsigned short* lbase;
    int ginc;
    if (wid < 2) {
        int row0 = wid * 64 + srow;
        int cg   = slot ^ ((row0 >> 1) & 3);
        gsrc  = Wt + (size_t)(bm0 + row0) * KTOT + cg * 8;
        lbase = As + wid * 2048;
        ginc  = 16 * KTOT;
    } else {
        int row0 = (wid - 2) * 64 + srow;
        int cg   = slot ^ ((row0 >> 1) & 3);
        gsrc  = xt + (size_t)n * XTROWS * 256 + (size_t)(bt0 + row0) * 256 + cg * 8;
        lbase = Bs + (wid - 2) * 2048;
        ginc  = 16 * 256;
    }

    // fragment read offsets (elements); k-chunk wanted = quad, stored at quad^((row>>1)&3)
    const int swz = quad ^ ((l16 >> 1) & 3);
    const int wave_m = (wid & 1) * 64;
    const int wave_t = (wid >> 1) * 64;
    int aoff[4], boff[4];
    #pragma unroll
    for (int i = 0; i < 4; ++i) {
        aoff[i] = (wave_m + i * 16 + l16) * 32 + swz * 8;
        boff[i] = (wave_t + i * 16 + l16) * 32 + swz * 8;
    }

    facc4 acc[4][4] = {};

    for (int s = 0; s < 24; ++s) {
        #pragma unroll
        for (int i = 0; i < 4; ++i)
            async16(lbase + i * 512, gsrc + (size_t)i * ginc + s * 32);
        __syncthreads();                 // compiler emits vmcnt(0) drain before barrier
        frag8 af[4], bfr[4];
        #pragma unroll
        for (int i = 0; i < 4; ++i) af[i]  = *(const frag8*)(As + aoff[i]);
        #pragma unroll
        for (int i = 0; i < 4; ++i) bfr[i] = *(const frag8*)(Bs + boff[i]);
        #pragma unroll
        for (int mi = 0; mi < 4; ++mi)
            #pragma unroll
            for (int ti = 0; ti < 4; ++ti)
                acc[mi][ti] = __builtin_amdgcn_mfma_f32_16x16x32_bf16(
                    af[mi], bfr[ti], acc[mi][ti], 0, 0, 0);
        __syncthreads();
    }

    // epilogue: D row = quad*4+reg (= m), col = l16 (= t); regs span 2 co x 2 phase
    #pragma unroll
    for (int mi = 0; mi < 4; ++mi) {
        int m0  = bm0 + wave_m + mi * 16 + quad * 4;   // even
        int co0 = m0 >> 1;
        float b0 = bias[co0];
        float b1 = bias[co0 + 1];
        #pragma unroll
        for (int ti = 0; ti < 4; ++ti) {
            int t = bt0 + wave_t + ti * 16 + l16;
            facc4 v = acc[mi][ti];
            float* p0 = out + ((size_t)(n * CO_ + co0)) * DO_ + 2 * t;
            float* p1 = p0 + DO_;
            *(float2*)p0 = make_float2(v.x + b0, v.y + b0);
            *(float2*)p1 = make_float2(v.z + b1, v.w + b1);
        }
    }
}

// ---------------- fallback (round-1 verified kernel) ---------------------
__global__ __launch_bounds__(256) void upconv_fir_f32(
    const float* __restrict__ x, const float* __restrict__ w,
    const float* __restrict__ bias, float* __restrict__ out)
{
    __shared__ float ws[CI_][4];
    const int tid = threadIdx.x;
    const int co  = blockIdx.y;
    const int n   = blockIdx.z;
    {
        const float* wc = w + (size_t)co * CI_ * 3;
        ws[tid][0] = wc[tid * 3 + 0];
        ws[tid][1] = wc[tid * 3 + 1];
        ws[tid][2] = wc[tid * 3 + 2];
        ws[tid][3] = 0.f;
    }
    __syncthreads();
    const int t0 = (blockIdx.x * 256 + tid) * 8;
    const float* xn = x + (size_t)n * CI_ * D_;
    float s[10], g[9];
    #pragma unroll
    for (int k = 0; k < 10; ++k) s[k] = 0.f;
    #pragma unroll
    for (int k = 0; k < 9; ++k) g[k] = 0.f;
    #pragma unroll 2
    for (int ci = 0; ci < CI_; ++ci) {
        const float* xr = xn + ci * D_;
        float4 va = *(const float4*)(xr + t0);
        float4 vb = *(const float4*)(xr + t0 + 4);
        float  xm = (t0 > 0)      ? xr[t0 - 1] : 0.f;
        float  xp = (t0 + 8 < D_) ? xr[t0 + 8] : 0.f;
        float4 wv = *(const float4*)(&ws[ci][0]);
        const float w0 = wv.x, w1 = wv.y, w2 = wv.z;
        float xa[10];
        xa[0] = xm; xa[1] = va.x; xa[2] = va.y; xa[3] = va.z; xa[4] = va.w;
        xa[5] = vb.x; xa[6] = vb.y; xa[7] = vb.z; xa[8] = vb.w; xa[9] = xp;
        #pragma unroll
        for (int k = 0; k < 10; ++k) s[k] += w1 * xa[k];
        #pragma unroll
        for (int k = 0; k < 9; ++k)  g[k] += w0 * xa[k] + w2 * xa[k + 1];
    }
    const float b = bias[co];
    float o16[16];
    #pragma unroll
    for (int tt = 0; tt < 8; ++tt) {
        o16[2 * tt]     = 0.25f * (s[tt] + g[tt + 1]) + 0.75f * (g[tt] + s[tt + 1]) + b;
        o16[2 * tt + 1] = 0.25f * (g[tt] + s[tt + 2]) + 0.75f * (s[tt + 1] + g[tt + 1]) + b;
    }
    float* ob = out + ((size_t)n * CO_ + co) * DO_ + 2 * t0;
    *(float4*)(ob + 0)  = make_float4(o16[0],  o16[1],  o16[2],  o16[3]);
    *(float4*)(ob + 4)  = make_float4(o16[4],  o16[5],  o16[6],  o16[7]);
    *(float4*)(ob + 8)  = make_float4(o16[8],  o16[9],  o16[10], o16[11]);
    *(float4*)(ob + 12) = make_float4(o16[12], o16[13], o16[14], o16[15]);
}

extern "C" void kernel_launch(void* const* d_in, const int* in_sizes, int n_in,
                              void* d_out, int out_size, void* d_ws, size_t ws_size,
                              hipStream_t stream) {
    const float* x  = (const float*)d_in[0];
    const float* w  = (const float*)d_in[1];
    const float* b  = (const float*)d_in[2];
    float* out      = (float*)d_out;

    const size_t need = (size_t)WT_ELEMS * 2 + XT_ELEMS * 2;
    if (ws_size >= need) {
        unsigned short* Wt = (unsigned short*)d_ws;
        unsigned short* xt = Wt + WT_ELEMS;
        prep_wt<<<dim3(CO_), 256, 0, stream>>>(w, Wt);
        prep_xt<<<dim3(D_ / 64, N_), 256, 0, stream>>>(x, xt);
        gemm_upfir<<<dim3(D_ / 128, 4, N_), 256, 0, stream>>>(Wt, xt, b, out);
    } else {
        upconv_fir_f32<<<dim3(2, CO_, N_), 256, 0, stream>>>(x, w, b, out);
    }
}

// Round 3
// 243.955 us; speedup vs baseline: 9.7048x; 1.0033x over previous
//
#include <hip/hip_runtime.h>
#include <hip/hip_bf16.h>

#define N_   16
#define CI_  256
#define CO_  256
#define D_   4096
#define DO_  8192
#define KTOT 768            // 3 taps (j outer) x 256 ci
#define XTROWS 4098         // 4096 t + 1 zero pad row each side
#define WT_ELEMS (512 * KTOT)
#define XT_ELEMS ((size_t)N_ * XTROWS * 256)

typedef short frag8 __attribute__((ext_vector_type(8)));   // 8 bf16 (4 VGPR)
typedef float facc4 __attribute__((ext_vector_type(4)));   // 4 f32 acc

static __device__ __forceinline__ unsigned short f2bf(float f) {
    union { __hip_bfloat16 h; unsigned short u; } cv;
    cv.h = __float2bfloat16(f);
    return cv.u;
}

static __device__ __forceinline__ unsigned int pack2(float lo, float hi) {
    return (unsigned int)f2bf(lo) | ((unsigned int)f2bf(hi) << 16);
}

static __device__ __forceinline__ void async16(unsigned short* lds, const unsigned short* g) {
    __builtin_amdgcn_global_load_lds(
        (const __attribute__((address_space(1))) unsigned int*)g,
        (__attribute__((address_space(3))) unsigned int*)lds, 16, 0, 0);
}

// ---------------- prep 1: effective bf16 weights -------------------------
// Wt[m = co*2+phase][k = j*256 + ci]; j=0 -> x[t-1], j=1 -> x[t], j=2 -> x[t+1]
__global__ __launch_bounds__(256) void prep_wt(const float* __restrict__ w,
                                               unsigned short* __restrict__ Wt) {
    const int ci = threadIdx.x;
    const int co = blockIdx.x;
    const float* wp = w + ((size_t)co * CI_ + ci) * 3;
    const float w0 = wp[0], w1 = wp[1], w2 = wp[2];
    const float e0 = 0.25f * w1 + 0.75f * w0;
    const float e1 = 0.75f * w2 + 0.75f * w1 + 0.25f * w0;
    const float e2 = 0.25f * w2;
    const float o0 = 0.25f * w0;
    const float o1 = 0.25f * w2 + 0.75f * w1 + 0.75f * w0;
    const float o2 = 0.75f * w2 + 0.25f * w1;
    unsigned short* pe = Wt + (size_t)(co * 2 + 0) * KTOT;
    unsigned short* po = Wt + (size_t)(co * 2 + 1) * KTOT;
    pe[0 * 256 + ci] = f2bf(e0); pe[1 * 256 + ci] = f2bf(e1); pe[2 * 256 + ci] = f2bf(e2);
    po[0 * 256 + ci] = f2bf(o0); po[1 * 256 + ci] = f2bf(o1); po[2 * 256 + ci] = f2bf(o2);
}

// ---------------- prep 2: x [n][ci][t] f32 -> x_t [n][t+1][ci] bf16 ------
// Block tile: 32 t x 256 ci. float4 loads (128B runs per ci row), packed-u32
// LDS transpose (pitch 133 -> max 2-way write conflicts = free), uint4
// coalesced stores (32 lanes cover one 512B t-row).
__global__ __launch_bounds__(256) void prep_xt2(const float* __restrict__ x,
                                                unsigned short* __restrict__ xt) {
    __shared__ unsigned int Lp[32][133];   // [t][ci_pair], pitch 133
    const int tid = threadIdx.x;
    const int t0  = blockIdx.x * 32;
    const int n   = blockIdx.y;
    const float* xn = x + (size_t)n * CI_ * D_;
    unsigned short* slab = xt + (size_t)n * XTROWS * 256;

    // zero pad rows (t = -1 and t = 4096), each 512B = 128 u32
    if (t0 == 0 && tid < 128)       ((unsigned int*)slab)[tid] = 0u;
    if (t0 == D_ - 32 && tid < 128) ((unsigned int*)(slab + (size_t)(XTROWS - 1) * 256))[tid] = 0u;

    const int cp_l  = tid >> 3;        // 0..31  (ci-pair within pass)
    const int t_off = (tid & 7) * 4;   // 0,4,...,28

    #pragma unroll
    for (int p = 0; p < 4; ++p) {
        const int ci0 = p * 64 + cp_l * 2;
        float4 a = *(const float4*)(xn + (size_t)ci0 * D_ + t0 + t_off);
        float4 b = *(const float4*)(xn + (size_t)(ci0 + 1) * D_ + t0 + t_off);
        const int cp = p * 32 + cp_l;
        Lp[t_off + 0][cp] = pack2(a.x, b.x);
        Lp[t_off + 1][cp] = pack2(a.y, b.y);
        Lp[t_off + 2][cp] = pack2(a.z, b.z);
        Lp[t_off + 3][cp] = pack2(a.w, b.w);
    }
    __syncthreads();

    // write: 4 iters x 8 rows; 32 lanes x 16B = one full 512B t-row
    #pragma unroll
    for (int it = 0; it < 4; ++it) {
        const int row = it * 8 + (tid >> 5);
        const int c4  = (tid & 31) * 4;           // u32 index within row
        uint4 v;
        v.x = Lp[row][c4 + 0];
        v.y = Lp[row][c4 + 1];
        v.z = Lp[row][c4 + 2];
        v.w = Lp[row][c4 + 3];
        *(uint4*)(slab + (size_t)(1 + t0 + row) * 256 + c4 * 2) = v;
    }
}

// ---------------- main: 128x128-tile bf16 MFMA GEMM + fused epilogue -----
// C[m][t] = sum_k Wt[m][k] * B[k][t],  B[k][t] = xt[n][t+1][k-part] (j offsets
// fold into row offsets -1/0/+1 via the overlapping [t][ci] layout)
__global__ __launch_bounds__(256) void gemm_upfir(
    const unsigned short* __restrict__ Wt, const unsigned short* __restrict__ xt,
    const float* __restrict__ bias, float* __restrict__ out)
{
    __shared__ __align__(16) unsigned short As[128 * 32];
    __shared__ __align__(16) unsigned short Bs[128 * 32];

    const int tid  = threadIdx.x;
    const int lane = tid & 63;
    const int wid  = tid >> 6;
    const int quad = lane >> 4;
    const int l16  = lane & 15;

    const int bt0 = blockIdx.x * 128;   // t tile
    const int bm0 = blockIdx.y * 128;   // m tile (m = co*2+phase)
    const int n   = blockIdx.z;

    // staging: 16 x 1KB global_load_lds per K-step; waves 0,1 -> As, 2,3 -> Bs
    // LDS chunk slot holds global chunk slot ^ ((row>>1)&3)  (bank swizzle)
    const int srow = lane >> 2;
    const int slot = lane & 3;
    const unsigned short* gsrc;
    unsigned short* lbase;
    int ginc;
    if (wid < 2) {
        int row0 = wid * 64 + srow;
        int cg   = slot ^ ((row0 >> 1) & 3);
        gsrc  = Wt + (size_t)(bm0 + row0) * KTOT + cg * 8;
        lbase = As + wid * 2048;
        ginc  = 16 * KTOT;
    } else {
        int row0 = (wid - 2) * 64 + srow;
        int cg   = slot ^ ((row0 >> 1) & 3);
        gsrc  = xt + (size_t)n * XTROWS * 256 + (size_t)(bt0 + row0) * 256 + cg * 8;
        lbase = Bs + (wid - 2) * 2048;
        ginc  = 16 * 256;
    }

    const int swz = quad ^ ((l16 >> 1) & 3);
    const int wave_m = (wid & 1) * 64;
    const int wave_t = (wid >> 1) * 64;
    int aoff[4], boff[4];
    #pragma unroll
    for (int i = 0; i < 4; ++i) {
        aoff[i] = (wave_m + i * 16 + l16) * 32 + swz * 8;
        boff[i] = (wave_t + i * 16 + l16) * 32 + swz * 8;
    }

    facc4 acc[4][4] = {};

    for (int s = 0; s < 24; ++s) {
        #pragma unroll
        for (int i = 0; i < 4; ++i)
            async16(lbase + i * 512, gsrc + (size_t)i * ginc + s * 32);
        __syncthreads();
        frag8 af[4], bfr[4];
        #pragma unroll
        for (int i = 0; i < 4; ++i) af[i]  = *(const frag8*)(As + aoff[i]);
        #pragma unroll
        for (int i = 0; i < 4; ++i) bfr[i] = *(const frag8*)(Bs + boff[i]);
        #pragma unroll
        for (int mi = 0; mi < 4; ++mi)
            #pragma unroll
            for (int ti = 0; ti < 4; ++ti)
                acc[mi][ti] = __builtin_amdgcn_mfma_f32_16x16x32_bf16(
                    af[mi], bfr[ti], acc[mi][ti], 0, 0, 0);
        __syncthreads();
    }

    // epilogue: D row = quad*4+reg (= m), col = l16 (= t); regs span 2 co x 2 phase
    #pragma unroll
    for (int mi = 0; mi < 4; ++mi) {
        int m0  = bm0 + wave_m + mi * 16 + quad * 4;
        int co0 = m0 >> 1;
        float b0 = bias[co0];
        float b1 = bias[co0 + 1];
        #pragma unroll
        for (int ti = 0; ti < 4; ++ti) {
            int t = bt0 + wave_t + ti * 16 + l16;
            facc4 v = acc[mi][ti];
            float* p0 = out + ((size_t)(n * CO_ + co0)) * DO_ + 2 * t;
            float* p1 = p0 + DO_;
            *(float2*)p0 = make_float2(v.x + b0, v.y + b0);
            *(float2*)p1 = make_float2(v.z + b1, v.w + b1);
        }
    }
}

// ---------------- fallback (round-1 verified kernel) ---------------------
__global__ __launch_bounds__(256) void upconv_fir_f32(
    const float* __restrict__ x, const float* __restrict__ w,
    const float* __restrict__ bias, float* __restrict__ out)
{
    __shared__ float ws[CI_][4];
    const int tid = threadIdx.x;
    const int co  = blockIdx.y;
    const int n   = blockIdx.z;
    {
        const float* wc = w + (size_t)co * CI_ * 3;
        ws[tid][0] = wc[tid * 3 + 0];
        ws[tid][1] = wc[tid * 3 + 1];
        ws[tid][2] = wc[tid * 3 + 2];
        ws[tid][3] = 0.f;
    }
    __syncthreads();
    const int t0 = (blockIdx.x * 256 + tid) * 8;
    const float* xn = x + (size_t)n * CI_ * D_;
    float s[10], g[9];
    #pragma unroll
    for (int k = 0; k < 10; ++k) s[k] = 0.f;
    #pragma unroll
    for (int k = 0; k < 9; ++k) g[k] = 0.f;
    #pragma unroll 2
    for (int ci = 0; ci < CI_; ++ci) {
        const float* xr = xn + ci * D_;
        float4 va = *(const float4*)(xr + t0);
        float4 vb = *(const float4*)(xr + t0 + 4);
        float  xm = (t0 > 0)      ? xr[t0 - 1] : 0.f;
        float  xp = (t0 + 8 < D_) ? xr[t0 + 8] : 0.f;
        float4 wv = *(const float4*)(&ws[ci][0]);
        const float w0 = wv.x, w1 = wv.y, w2 = wv.z;
        float xa[10];
        xa[0] = xm; xa[1] = va.x; xa[2] = va.y; xa[3] = va.z; xa[4] = va.w;
        xa[5] = vb.x; xa[6] = vb.y; xa[7] = vb.z; xa[8] = vb.w; xa[9] = xp;
        #pragma unroll
        for (int k = 0; k < 10; ++k) s[k] += w1 * xa[k];
        #pragma unroll
        for (int k = 0; k < 9; ++k)  g[k] += w0 * xa[k] + w2 * xa[k + 1];
    }
    const float b = bias[co];
    float o16[16];
    #pragma unroll
    for (int tt = 0; tt < 8; ++tt) {
        o16[2 * tt]     = 0.25f * (s[tt] + g[tt + 1]) + 0.75f * (g[tt] + s[tt + 1]) + b;
        o16[2 * tt + 1] = 0.25f * (g[tt] + s[tt + 2]) + 0.75f * (s[tt + 1] + g[tt + 1]) + b;
    }
    float* ob = out + ((size_t)n * CO_ + co) * DO_ + 2 * t0;
    *(float4*)(ob + 0)  = make_float4(o16[0],  o16[1],  o16[2],  o16[3]);
    *(float4*)(ob + 4)  = make_float4(o16[4],  o16[5],  o16[6],  o16[7]);
    *(float4*)(ob + 8)  = make_float4(o16[8],  o16[9],  o16[10], o16[11]);
    *(float4*)(ob + 12) = make_float4(o16[12], o16[13], o16[14], o16[15]);
}

extern "C" void kernel_launch(void* const* d_in, const int* in_sizes, int n_in,
                              void* d_out, int out_size, void* d_ws, size_t ws_size,
                              hipStream_t stream) {
    const float* x  = (const float*)d_in[0];
    const float* w  = (const float*)d_in[1];
    const float* b  = (const float*)d_in[2];
    float* out      = (float*)d_out;

    const size_t need = (size_t)WT_ELEMS * 2 + XT_ELEMS * 2;
    if (ws_size >= need) {
        unsigned short* Wt = (unsigned short*)d_ws;
        unsigned short* xt = Wt + WT_ELEMS;
        prep_wt<<<dim3(CO_), 256, 0, stream>>>(w, Wt);
        prep_xt2<<<dim3(D_ / 32, N_), 256, 0, stream>>>(x, xt);
        gemm_upfir<<<dim3(D_ / 128, 4, N_), 256, 0, stream>>>(Wt, xt, b, out);
    } else {
        upconv_fir_f32<<<dim3(2, CO_, N_), 256, 0, stream>>>(x, w, b, out);
    }
}